// Round 14
// baseline (686.601 us; speedup 1.0000x reference)
//
#include <hip/hip_runtime.h>
#include <stdint.h>

#define D_MODEL 1024
#define EXP_D   4096
#define NE      8
#define NTOK    8192
#define MAXT256 72
#define MAXT128H 144

typedef __attribute__((ext_vector_type(8))) short short8;
typedef __attribute__((ext_vector_type(4))) float f32x4;
typedef __attribute__((ext_vector_type(4))) unsigned short us4;

// ---- workspace layout (bytes) ----
#define WS_CURSORS   32         // int[8]
#define WS_PADOFF    64         // int[16]
#define WS_META      128        // int[32], meta[0]=nt (256-tiles), meta[1]=2*nt
#define WS_TILE_E    256        // int[960]
#define WS_PP        4096       // float[2048*8]
#define WS_TOP_E     69632      // int[16384]
#define WS_TOP_W     135168     // float[16384]
#define WS_TOK_RANK  200704     // int[16384] -> ends 266240
#define WS_SLOT_W    266240     // float[18432] -> ends 339968 (memset 0; pads stay 0)
#define WS_SLOT_TOK  339968     // int[18432] -> ends 413696 (only real slots written)
#define WS_XG        413696     // bf16 rows x 1024; real rows <= 18424 -> ends 38,146,048
#define WS_HB        38158336   // bf16 18432 x 4096 -> ends 189,153,280
#define WS_WB        189153280  // bf16 [8][4096][1024] -> ends 256,262,144 (proven ws bound)
#define WS_WB2       256262144  // bf16 [8][1024][4096] (only if ws >= REQ_BIG2)
#define REQ_BIG2     323371008ull

__device__ __forceinline__ unsigned short f2bf(float f){
  __bf16 h = (__bf16)f;
  return __builtin_bit_cast(unsigned short, h);
}
__device__ __forceinline__ float bf2f(unsigned short u){
  unsigned int v = ((unsigned int)u) << 16;
  return __builtin_bit_cast(float, v);
}
__device__ __forceinline__ void gl_lds16(const void* g, void* l){
  __builtin_amdgcn_global_load_lds((const __attribute__((address_space(1))) unsigned int*)g,
                                   (__attribute__((address_space(3))) unsigned int*)l,
                                   16, 0, 0);
}

template<int N> __device__ __forceinline__ void vmw(){
  if constexpr (N==0)      asm volatile("s_waitcnt vmcnt(0)" ::: "memory");
  else if constexpr (N==2) asm volatile("s_waitcnt vmcnt(2)" ::: "memory");
  else if constexpr (N==4) asm volatile("s_waitcnt vmcnt(4)" ::: "memory");
  else if constexpr (N==6) asm volatile("s_waitcnt vmcnt(6)" ::: "memory");
}

// ---------------- router (blocks 0..2047, NO atomics) + weight cvt (blocks >=2048) ----------------
__global__ __launch_bounds__(256) void router_cvt_kernel(
    const float* __restrict__ x, const float* __restrict__ Wr,
    const float* __restrict__ br,
    int* __restrict__ top_e, float* __restrict__ top_w,
    float* __restrict__ pp,
    const float* __restrict__ W1, unsigned short* __restrict__ Wb,
    const float* __restrict__ W2, unsigned short* __restrict__ W2b,
    int cvt_total4)
{
  const int tid = threadIdx.x;
  if ((int)blockIdx.x >= NTOK/4){
    const int n4 = NE*EXP_D*D_MODEL/4;
    const int stride = ((int)gridDim.x - NTOK/4)*256;
    for (int i = ((int)blockIdx.x - NTOK/4)*256 + tid; i < cvt_total4; i += stride){
      if (i < n4){
        const float4 v = *(const float4*)&W1[(size_t)i*4];
        us4 o; o[0]=f2bf(v.x); o[1]=f2bf(v.y); o[2]=f2bf(v.z); o[3]=f2bf(v.w);
        *(us4*)&Wb[(size_t)i*4] = o;
      } else {
        const int j = i - n4;
        const float4 v = *(const float4*)&W2[(size_t)j*4];
        us4 o; o[0]=f2bf(v.x); o[1]=f2bf(v.y); o[2]=f2bf(v.z); o[3]=f2bf(v.w);
        *(us4*)&W2b[(size_t)j*4] = o;
      }
    }
    return;
  }
  __shared__ float WrS[NE*D_MODEL];
  __shared__ float wprob[4][NE];
#pragma unroll
  for (int i=0;i<8;++i){
    int j = (tid + i*256)*4;
    *(float4*)&WrS[j] = *(const float4*)&Wr[j];
  }
  __syncthreads();
  const int w = tid>>6, lane = tid&63;
  const int t = blockIdx.x*4 + w;
  const float* xt = x + (size_t)t*D_MODEL;
  float accv[8] = {0,0,0,0,0,0,0,0};
#pragma unroll
  for (int i=0;i<4;++i){
    const int k = i*256 + lane*4;
    const float4 xv = *(const float4*)&xt[k];
#pragma unroll
    for (int e=0;e<8;++e){
      const float4 wv = *(const float4*)&WrS[e*D_MODEL + k];
      accv[e] += xv.x*wv.x + xv.y*wv.y + xv.z*wv.z + xv.w*wv.w;
    }
  }
#pragma unroll
  for (int m=32;m>0;m>>=1){
#pragma unroll
    for (int e=0;e<8;++e) accv[e] += __shfl_xor(accv[e], m, 64);
  }
  if (lane==0){
    float lg[8];
#pragma unroll
    for (int e=0;e<8;++e) lg[e] = accv[e] + br[e];
    float mx = lg[0];
#pragma unroll
    for (int e=1;e<8;++e) mx = fmaxf(mx, lg[e]);
    float p[8]; float s=0.f;
#pragma unroll
    for (int e=0;e<8;++e){ p[e] = __expf(lg[e]-mx); s += p[e]; }
    const float inv = 1.f/s;
#pragma unroll
    for (int e=0;e<8;++e){ p[e] *= inv; wprob[w][e] = p[e]; }
    int i1=0; float p1v=p[0];
#pragma unroll
    for (int e=1;e<8;++e) if (p[e] > p1v){ p1v=p[e]; i1=e; }
    int i2=-1; float p2v=-1.f;
#pragma unroll
    for (int e=0;e<8;++e) if (e!=i1 && p[e] > p2v){ p2v=p[e]; i2=e; }
    const float rn = 1.f/(p1v+p2v);
    top_e[2*t]   = i1; top_w[2*t]   = p1v*rn;
    top_e[2*t+1] = i2; top_w[2*t+1] = p2v*rn;
  }
  __syncthreads();
  if (tid<8){
    pp[blockIdx.x*8+tid] = wprob[0][tid]+wprob[1][tid]+wprob[2][tid]+wprob[3][tid];
  }
}

// ---------------- standalone cvt (fallback, W2) ----------------
__global__ __launch_bounds__(256) void cvt_kernel(const float* __restrict__ W,
                                                  unsigned short* __restrict__ Wb){
  const int n4 = NE*EXP_D*D_MODEL/4;
  for (int i = blockIdx.x*256 + threadIdx.x; i < n4; i += gridDim.x*256){
    const float4 v = *(const float4*)&W[(size_t)i*4];
    us4 o; o[0]=f2bf(v.x); o[1]=f2bf(v.y); o[2]=f2bf(v.z); o[3]=f2bf(v.w);
    *(us4*)&Wb[(size_t)i*4] = o;
  }
}

// ---------------- scatter: LDS-aggregated counting + expert-local ranks ----------------
__global__ __launch_bounds__(1024) void scatter_kernel(
    const int* __restrict__ top_e,
    int* __restrict__ cursors, int* __restrict__ tok_rank)
{
  __shared__ int cnt[NE];
  __shared__ int base[NE];
  const int tid = threadIdx.x;
  if (tid < NE) cnt[tid] = 0;
  __syncthreads();
  const int t = blockIdx.x*1024 + tid;
  const int e0 = top_e[2*t], e1 = top_e[2*t+1];
  const int p0 = atomicAdd(&cnt[e0], 1);
  const int p1 = atomicAdd(&cnt[e1], 1);
  __syncthreads();
  if (tid < NE) base[tid] = atomicAdd(&cursors[tid], cnt[tid]);
  __syncthreads();
  tok_rank[2*t]   = base[e0] + p0;
  tok_rank[2*t+1] = base[e1] + p1;
}

// ---------------- prefix (AFTER scatter): tile table (256-pad) + aux ----------------
__global__ __launch_bounds__(256) void prefix_kernel(int* __restrict__ wsI,
                                                     const float* __restrict__ pp,
                                                     float* __restrict__ aux_out){
  const int tid = threadIdx.x;
  int* counts = wsI + 8;
  int* padoff = wsI + 16;
  int* meta   = wsI + 32;
  int* tileE  = wsI + 64;
  __shared__ int tileCum[9];
  __shared__ float dev2[8];
  if (tid==0){
    int nt = 0;
    tileCum[0] = 0;
    for (int e=0;e<NE;++e){
      padoff[e] = nt << 8;
      nt += (counts[e] + 255) >> 8;
      tileCum[e+1] = nt;
    }
    meta[0] = nt;
    meta[1] = 2*nt;
  }
  __syncthreads();
  const int nt = tileCum[8];
  for (int i=tid; i<nt; i+=256){
    int e = 0;
    while (tileCum[e+1] <= i) ++e;
    tileE[i] = e;
  }
  const int ex = tid>>5, j = tid&31;
  float s = 0.f;
  for (int b=j; b<NTOK/4; b+=32) s += pp[b*8+ex];
#pragma unroll
  for (int m=16;m>0;m>>=1) s += __shfl_xor(s, m, 64);
  if (j==0){ float d = s*(1.f/(float)NTOK) - 0.125f; dev2[ex] = d*d; }
  __syncthreads();
  if (tid==0){
    float a=0.f;
#pragma unroll
    for (int e=0;e<8;++e) a += dev2[e];
    aux_out[0] = a;
  }
}

// ---------------- gather: slot = padoff[e] + rank; write slot_tok/slot_w/Xg rows ----------------
__global__ __launch_bounds__(256) void gather_kernel(
    const float* __restrict__ x, const int* __restrict__ top_e,
    const float* __restrict__ top_w, const int* __restrict__ tok_rank,
    const int* __restrict__ padoff,
    int* __restrict__ slot_tok, float* __restrict__ slot_w,
    unsigned short* __restrict__ Xg)
{
  const int w = threadIdx.x>>6, lane = threadIdx.x&63;
  const int t = blockIdx.x*4 + w;
  const int s0 = padoff[top_e[2*t]]   + tok_rank[2*t];
  const int s1 = padoff[top_e[2*t+1]] + tok_rank[2*t+1];
  if (lane==0){
    slot_tok[s0] = t; slot_tok[s1] = t;
    slot_w[s0] = top_w[2*t]; slot_w[s1] = top_w[2*t+1];
  }
  us4 o[4];
#pragma unroll
  for (int i=0;i<4;++i){
    const float4 v = *(const float4*)&x[(size_t)t*D_MODEL + i*256 + lane*4];
    o[i][0]=f2bf(v.x); o[i][1]=f2bf(v.y); o[i][2]=f2bf(v.z); o[i][3]=f2bf(v.w);
  }
#pragma unroll
  for (int i=0;i<4;++i) *(us4*)&Xg[(size_t)s0*D_MODEL + i*256 + lane*4] = o[i];
#pragma unroll
  for (int i=0;i<4;++i) *(us4*)&Xg[(size_t)s1*D_MODEL + i*256 + lane*4] = o[i];
}

// ============ GEMM1: 256x256 tile, BK=64, 8 waves (128x64/wave), 2-buf, B-held-in-regs ============
template<int KT, int NT>
__global__ __launch_bounds__(512,1) void moe_g256b(
    const unsigned short* __restrict__ A,
    const unsigned short* __restrict__ Wb,
    const float* __restrict__ bias,
    unsigned short* __restrict__ Cout,
    const int* __restrict__ tileE,
    const int* __restrict__ meta)
{
  constexpr int NX = NT/256;
  constexpr int TOTAL = NX*MAXT256;
  constexpr int Q = TOTAL/8, R = TOTAL%8;
  constexpr int NTILES = KT/64;
  static_assert(NTILES>=3, "min K");

  const int lid = blockIdx.x;
  const int xcc = lid & 7, jj = lid >> 3;
  const int tsw = xcc*Q + (xcc < R ? xcc : R) + jj;
  const int mtile = tsw / NX, ntile = tsw - mtile*NX;
  if (mtile >= meta[0]) return;

  extern __shared__ char smem[];
  char* const BUF0 = smem;
  char* const BUF1 = smem + 65536;

  const int tid = threadIdx.x;
  const int w = tid>>6, lane = tid&63;
  const int wr = w>>2, wn = w&3;
  const int r15 = lane&15, kg = lane>>4;
  const int e  = tileE[mtile];
  const int m0 = mtile*256;
  const int n0 = ntile*256;

  const int trow = tid>>3;
  const int tch  = ((tid&7) ^ (trow&7))*8;
  const unsigned short* sA = A  + (size_t)(m0 + trow)*KT + tch;
  const unsigned short* sB = Wb + (size_t)e*NT*KT + (size_t)(n0 + trow)*KT + tch;

#define SG_B01(BS,KTT) do{ \
  gl_lds16(sB + (size_t)(KTT)*64,                  (BS)+32768+tid*16); \
  gl_lds16(sB + (size_t)(KTT)*64 + (size_t)64*KT,  (BS)+40960+tid*16); }while(0)
#define SG_B23(BS,KTT) do{ \
  gl_lds16(sB + (size_t)(KTT)*64 + (size_t)128*KT, (BS)+49152+tid*16); \
  gl_lds16(sB + (size_t)(KTT)*64 + (size_t)192*KT, (BS)+57344+tid*16); }while(0)
#define SG_A02(BS,KTT) do{ \
  gl_lds16(sA + (size_t)(KTT)*64,                  (BS)+tid*16); \
  gl_lds16(sA + (size_t)(KTT)*64 + (size_t)128*KT, (BS)+16384+tid*16); }while(0)
#define SG_A13(BS,KTT) do{ \
  gl_lds16(sA + (size_t)(KTT)*64 + (size_t)64*KT,  (BS)+8192+tid*16); \
  gl_lds16(sA + (size_t)(KTT)*64 + (size_t)192*KT, (BS)+24576+tid*16); }while(0)

  const int key4 = (kg ^ (r15&7))<<4;
  const int aw = (wr*128 + r15)*128 + key4;
  const int bw = 32768 + (wn*64 + r15)*128 + key4;

  f32x4 acc[8][4];
#pragma unroll
  for (int i=0;i<8;++i)
#pragma unroll
    for (int j=0;j<4;++j) acc[i][j] = (f32x4){0.f,0.f,0.f,0.f};

  short8 Bq[8], Aq[4];

#define RD_BALL(BC) do{ _Pragma("unroll") for(int nf=0;nf<4;++nf){ \
    const int off_ = bw + nf*2048; \
    Bq[nf*2]   = *(const short8*)((BC)+off_); \
    Bq[nf*2+1] = *(const short8*)((BC)+(off_^64)); }}while(0)
#define RD_A4(BC, MB, KS) do{ _Pragma("unroll") for(int mi=0;mi<4;++mi){ \
    Aq[mi] = *(const short8*)((BC)+((aw + ((MB)+mi)*2048) ^ ((KS)*64))); }}while(0)

#define MF16(MB, KS) \
  _Pragma("unroll") for(int mi=0;mi<4;++mi) \
  _Pragma("unroll") for(int nf=0;nf<4;++nf) \
    acc[(MB)+mi][nf]=__builtin_amdgcn_mfma_f32_16x16x32_bf16(Bq[nf*2+(KS)],Aq[mi],acc[(MB)+mi][nf],0,0,0);

#define PH_TAIL(MFS) \
    __builtin_amdgcn_sched_barrier(0); \
    __builtin_amdgcn_s_barrier(); \
    asm volatile("s_waitcnt lgkmcnt(0)" ::: "memory"); \
    __builtin_amdgcn_sched_barrier(0); \
    __builtin_amdgcn_s_setprio(1); \
    MFS \
    __builtin_amdgcn_s_setprio(0); \
    __builtin_amdgcn_sched_barrier(0); \
    __builtin_amdgcn_s_barrier();

#define TILEB(BC,BS,KTN,DOSTG,VM1,VM3) do{ \
    RD_BALL(BC); RD_A4(BC,0,0); if(DOSTG){ SG_B01(BS,KTN); } \
    PH_TAIL(MF16(0,0)) \
    RD_A4(BC,0,1); if(DOSTG){ SG_B23(BS,KTN); } \
    VM1; \
    PH_TAIL(MF16(0,1)) \
    RD_A4(BC,4,0); if(DOSTG){ SG_A02(BS,KTN); } \
    PH_TAIL(MF16(4,0)) \
    RD_A4(BC,4,1); if(DOSTG){ SG_A13(BS,KTN); } \
    VM3; \
    PH_TAIL(MF16(4,1)) \
  }while(0)

  SG_B01(BUF0,0); SG_B23(BUF0,0); SG_A02(BUF0,0); SG_A13(BUF0,0);
  vmw<2>();
  __builtin_amdgcn_s_barrier();

#pragma unroll 1
  for (int t = 0; t < NTILES-1; ++t){
    const char* BC = (t&1) ? BUF1 : BUF0;
    char* BS = (t&1) ? BUF0 : BUF1;
    TILEB(BC, BS, t+1, true, vmw<4>(), vmw<2>());
  }
  {
    const char* BC = ((NTILES-1)&1) ? BUF1 : BUF0;
    TILEB(BC, BUF0, 0, false, vmw<0>(), (void)0);
  }
#undef TILEB
#undef PH_TAIL
#undef MF16
#undef RD_A4
#undef RD_BALL
#undef SG_B01
#undef SG_B23
#undef SG_A02
#undef SG_A13

  const int ng4 = kg*4;
#pragma unroll
  for (int mi=0; mi<8; ++mi){
    const int m = m0 + wr*128 + mi*16 + r15;
#pragma unroll
    for (int nf=0; nf<4; ++nf){
      const int nb = n0 + wn*64 + nf*16 + ng4;
      const float4 bv = *(const float4*)&bias[(size_t)e*NT + nb];
      float q0 = fmaxf(acc[mi][nf][0] + bv.x, 0.f);
      float q1 = fmaxf(acc[mi][nf][1] + bv.y, 0.f);
      float q2 = fmaxf(acc[mi][nf][2] + bv.z, 0.f);
      float q3 = fmaxf(acc[mi][nf][3] + bv.w, 0.f);
      us4 o; o[0]=f2bf(q0); o[1]=f2bf(q1); o[2]=f2bf(q2); o[3]=f2bf(q3);
      *(us4*)&Cout[(size_t)m*NT + nb] = o;
    }
  }
}

// ============ GEMM2: 128x256, BK=64, 8 waves, 3-buf pipeline; atomic-combine epilogue ============
template<int KT, int NT, int MAXT>
__global__ __launch_bounds__(512,1) void moe_gemm3(
    const unsigned short* __restrict__ A,
    const unsigned short* __restrict__ Wb,
    const float* __restrict__ bias,
    float* __restrict__ out,
    const int* __restrict__ tileE,
    const int* __restrict__ meta,
    const float* __restrict__ slotw,
    const int* __restrict__ slot_tok)
{
  constexpr int NX = NT/256;
  constexpr int TOTAL = NX*MAXT;
  constexpr int Q = TOTAL/8, R = TOTAL%8;
  constexpr int NTILES = KT/64;
  constexpr int K3 = (NTILES-4)/3;
  static_assert((NTILES-4)%3 == 0, "tail peel needs (NTILES-4)%3==0");

  const int lid = blockIdx.x;
  const int xcc = lid & 7, jj = lid >> 3;
  const int tsw = xcc*Q + (xcc < R ? xcc : R) + jj;
  const int mtile = tsw / NX, ntile = tsw - mtile*NX;
  if (mtile >= meta[1]) return;

  extern __shared__ char smem[];
  char* const BUF0 = smem;
  char* const BUF1 = smem + 49152;
  char* const BUF2 = smem + 98304;

  const int tid = threadIdx.x;
  const int w = tid>>6, lane = tid&63;
  const int wr = w>>2, wn = w&3;
  const int r15 = lane&15, kg = lane>>4;
  const int e  = tileE[mtile>>1];
  const int m0 = mtile*128;
  const int n0 = ntile*256;

  const int trow = tid>>3;
  const int tch  = ((tid&7) ^ (trow&7))*8;
  const unsigned short* sA = A  + (size_t)(m0 + trow)*KT + tch;
  const unsigned short* sB = Wb + (size_t)e*NT*KT + (size_t)(n0 + trow)*KT + tch;

#define STG_ALL(BS, KTT) do{ \
    gl_lds16(sA + (size_t)(KTT)*64,                  (BS) + tid*16); \
    gl_lds16(sA + (size_t)(KTT)*64 + (size_t)64*KT,  (BS) + 8192  + tid*16); \
    gl_lds16(sB + (size_t)(KTT)*64,                  (BS) + 16384 + tid*16); \
    gl_lds16(sB + (size_t)(KTT)*64 + (size_t)64*KT,  (BS) + 24576 + tid*16); \
    gl_lds16(sB + (size_t)(KTT)*64 + (size_t)128*KT, (BS) + 32768 + tid*16); \
    gl_lds16(sB + (size_t)(KTT)*64 + (size_t)192*KT, (BS) + 40960 + tid*16); \
  }while(0)

  const int key4 = (kg ^ (r15&7))<<4;
  const int a0 = (wr*64 + 0*16 + r15)*128 + key4;
  const int a1 = (wr*64 + 1*16 + r15)*128 + key4;
  const int a2 = (wr*64 + 2*16 + r15)*128 + key4;
  const int a3 = (wr*64 + 3*16 + r15)*128 + key4;
  const int b0 = 16384 + (wn*64 + 0*16 + r15)*128 + key4;
  const int b1 = 16384 + (wn*64 + 1*16 + r15)*128 + key4;
  const int b2 = 16384 + (wn*64 + 2*16 + r15)*128 + key4;
  const int b3 = 16384 + (wn*64 + 3*16 + r15)*128 + key4;

  f32x4 acc[4][4];
#pragma unroll
  for (int i=0;i<4;++i)
#pragma unroll
    for (int j=0;j<4;++j) acc[i][j] = (f32x4){0.f,0.f,0.f,0.f};

  short8 A0[4], B0[4], A1[4], B1[4];

#define MFMA16(AX, BX) \
    acc[0][0]=__builtin_amdgcn_mfma_f32_16x16x32_bf16(BX[0],AX[0],acc[0][0],0,0,0); \
    acc[0][1]=__builtin_amdgcn_mfma_f32_16x16x32_bf16(BX[1],AX[0],acc[0][1],0,0,0); \
    acc[0][2]=__builtin_amdgcn_mfma_f32_16x16x32_bf16(BX[2],AX[0],acc[0][2],0,0,0); \
    acc[0][3]=__builtin_amdgcn_mfma_f32_16x16x32_bf16(BX[3],AX[0],acc[0][3],0,0,0); \
    acc[1][0]=__builtin_amdgcn_mfma_f32_16x16x32_bf16(BX[0],AX[1],acc[1][0],0,0,0); \
    acc[1][1]=__builtin_amdgcn_mfma_f32_16x16x32_bf16(BX[1],AX[1],acc[1][1],0,0,0); \
    acc[1][2]=__builtin_amdgcn_mfma_f32_16x16x32_bf16(BX[2],AX[1],acc[1][2],0,0,0); \
    acc[1][3]=__builtin_amdgcn_mfma_f32_16x16x32_bf16(BX[3],AX[1],acc[1][3],0,0,0); \
    acc[2][0]=__builtin_amdgcn_mfma_f32_16x16x32_bf16(BX[0],AX[2],acc[2][0],0,0,0); \
    acc[2][1]=__builtin_amdgcn_mfma_f32_16x16x32_bf16(BX[1],AX[2],acc[2][1],0,0,0); \
    acc[2][2]=__builtin_amdgcn_mfma_f32_16x16x32_bf16(BX[2],AX[2],acc[2][2],0,0,0); \
    acc[2][3]=__builtin_amdgcn_mfma_f32_16x16x32_bf16(BX[3],AX[2],acc[2][3],0,0,0); \
    acc[3][0]=__builtin_amdgcn_mfma_f32_16x16x32_bf16(BX[0],AX[3],acc[3][0],0,0,0); \
    acc[3][1]=__builtin_amdgcn_mfma_f32_16x16x32_bf16(BX[1],AX[3],acc[3][1],0,0,0); \
    acc[3][2]=__builtin_amdgcn_mfma_f32_16x16x32_bf16(BX[2],AX[3],acc[3][2],0,0,0); \
    acc[3][3]=__builtin_amdgcn_mfma_f32_16x16x32_bf16(BX[3],AX[3],acc[3][3],0,0,0);

#define RD_KS1(BC) do{ \
    A1[0] = *(const short8*)((BC) + (a0 ^ 64)); \
    A1[1] = *(const short8*)((BC) + (a1 ^ 64)); \
    A1[2] = *(const short8*)((BC) + (a2 ^ 64)); \
    A1[3] = *(const short8*)((BC) + (a3 ^ 64)); \
    B1[0] = *(const short8*)((BC) + (b0 ^ 64)); \
    B1[1] = *(const short8*)((BC) + (b1 ^ 64)); \
    B1[2] = *(const short8*)((BC) + (b2 ^ 64)); \
    B1[3] = *(const short8*)((BC) + (b3 ^ 64)); \
  }while(0)
#define RD_KS0(BN1) do{ \
    A0[0] = *(const short8*)((BN1) + a0); \
    A0[1] = *(const short8*)((BN1) + a1); \
    A0[2] = *(const short8*)((BN1) + a2); \
    A0[3] = *(const short8*)((BN1) + a3); \
    B0[0] = *(const short8*)((BN1) + b0); \
    B0[1] = *(const short8*)((BN1) + b1); \
    B0[2] = *(const short8*)((BN1) + b2); \
    B0[3] = *(const short8*)((BN1) + b3); \
  }while(0)

#define TILE(BC, BN1, STG_STMT, VM_STMT) do{ \
    RD_KS1(BC); \
    STG_STMT; \
    __builtin_amdgcn_sched_barrier(0); \
    __builtin_amdgcn_s_setprio(1); \
    MFMA16(A0, B0) \
    __builtin_amdgcn_s_setprio(0); \
    __builtin_amdgcn_sched_barrier(0); \
    VM_STMT; \
    asm volatile("s_waitcnt lgkmcnt(0)" ::: "memory"); \
    __builtin_amdgcn_sched_barrier(0); \
    __builtin_amdgcn_s_barrier(); \
    RD_KS0(BN1); \
    __builtin_amdgcn_sched_barrier(0); \
    __builtin_amdgcn_s_setprio(1); \
    MFMA16(A1, B1) \
    __builtin_amdgcn_s_setprio(0); \
    __builtin_amdgcn_sched_barrier(0); \
  }while(0)

  STG_ALL(BUF0, 0);
  STG_ALL(BUF1, 1);
  vmw<6>();
  __builtin_amdgcn_s_barrier();
  RD_KS0(BUF0);

#pragma unroll 1
  for (int i = 0; i < K3; ++i){
    const int kt = i*3;
    TILE(BUF0, BUF1, STG_ALL(BUF2, kt+2), vmw<6>());
    TILE(BUF1, BUF2, STG_ALL(BUF0, kt+3), vmw<6>());
    TILE(BUF2, BUF0, STG_ALL(BUF1, kt+4), vmw<6>());
  }
  TILE(BUF0, BUF1, STG_ALL(BUF2, NTILES-2), vmw<6>());
  TILE(BUF1, BUF2, STG_ALL(BUF0, NTILES-1), vmw<6>());
  TILE(BUF2, BUF0, (void)0, vmw<0>());
  {
    RD_KS1(BUF0);
    __builtin_amdgcn_sched_barrier(0);
    __builtin_amdgcn_s_setprio(1);
    MFMA16(A0, B0)
    __builtin_amdgcn_s_setprio(0);
    __builtin_amdgcn_sched_barrier(0);
    __builtin_amdgcn_s_setprio(1);
    MFMA16(A1, B1)
    __builtin_amdgcn_s_setprio(0);
  }
#undef TILE
#undef RD_KS0
#undef RD_KS1
#undef MFMA16
#undef STG_ALL

  // epilogue: out[token] += (acc+bias)*wg via f32 atomics (2 commutative addends -> deterministic)
  const int ng4 = kg*4;
#pragma unroll
  for (int mf=0; mf<4; ++mf){
    const int m = m0 + wr*64 + mf*16 + r15;
    const float wg = slotw[m];
    if (wg != 0.f){
      const int tok = slot_tok[m];
      float* orow = out + (size_t)tok*NT;
#pragma unroll
      for (int nf=0; nf<4; ++nf){
        const int nb = n0 + wn*64 + nf*16 + ng4;
        const float4 bv = *(const float4*)&bias[(size_t)e*NT + nb];
        atomicAdd(orow + nb + 0, (acc[mf][nf][0] + bv.x)*wg);
        atomicAdd(orow + nb + 1, (acc[mf][nf][1] + bv.y)*wg);
        atomicAdd(orow + nb + 2, (acc[mf][nf][2] + bv.z)*wg);
        atomicAdd(orow + nb + 3, (acc[mf][nf][3] + bv.w)*wg);
      }
    }
  }
}

extern "C" void kernel_launch(void* const* d_in, const int* in_sizes, int n_in,
                              void* d_out, int out_size, void* d_ws, size_t ws_size,
                              hipStream_t stream)
{
  const float* x  = (const float*)d_in[0];
  const float* Wr = (const float*)d_in[1];
  const float* br = (const float*)d_in[2];
  const float* W1 = (const float*)d_in[3];
  const float* b1 = (const float*)d_in[4];
  const float* W2 = (const float*)d_in[5];
  const float* b2 = (const float*)d_in[6];
  float* out = (float*)d_out;
  char* ws = (char*)d_ws;

  const bool fusedcvt = ws_size >= REQ_BIG2;

  int*   cursors = (int*)(ws + WS_CURSORS);
  int*   padoff  = (int*)(ws + WS_PADOFF);
  int*   meta    = (int*)(ws + WS_META);
  int*   tileE   = (int*)(ws + WS_TILE_E);
  float* pp      = (float*)(ws + WS_PP);
  int*   top_e   = (int*)(ws + WS_TOP_E);
  float* top_w   = (float*)(ws + WS_TOP_W);
  int*   tok_rank= (int*)(ws + WS_TOK_RANK);
  float* slot_w  = (float*)(ws + WS_SLOT_W);
  int*   slot_tok= (int*)(ws + WS_SLOT_TOK);
  unsigned short* Xg  = (unsigned short*)(ws + WS_XG);
  unsigned short* Hb  = (unsigned short*)(ws + WS_HB);
  unsigned short* Wb  = (unsigned short*)(ws + WS_WB);
  unsigned short* W2b = (unsigned short*)(ws + WS_WB2);

  hipFuncSetAttribute((const void*)moe_g256b<D_MODEL, EXP_D>,
                      hipFuncAttributeMaxDynamicSharedMemorySize, 131072);
  hipFuncSetAttribute((const void*)moe_gemm3<EXP_D, D_MODEL, MAXT128H>,
                      hipFuncAttributeMaxDynamicSharedMemorySize, 147456);

  const int n4 = NE*EXP_D*D_MODEL/4;
  hipMemsetAsync(ws, 0, 128, stream);                       // cursors zero
  hipMemsetAsync(slot_w, 0, 18432*sizeof(float), stream);   // pad slots -> wg=0
  hipMemsetAsync(out, 0, (size_t)out_size*sizeof(float), stream);  // atomic-accum base
  if (fusedcvt){
    router_cvt_kernel<<<dim3(NTOK/4 + 4096), dim3(256), 0, stream>>>(
        x, Wr, br, top_e, top_w, pp, W1, Wb, W2, W2b, 2*n4);
  } else {
    router_cvt_kernel<<<dim3(NTOK/4 + 2048), dim3(256), 0, stream>>>(
        x, Wr, br, top_e, top_w, pp, W1, Wb, W2, Wb, n4);
  }
  scatter_kernel<<<dim3(NTOK/1024), dim3(1024), 0, stream>>>(top_e, cursors, tok_rank);
  prefix_kernel<<<dim3(1), dim3(256), 0, stream>>>((int*)ws, pp, out + (size_t)NTOK*D_MODEL);
  gather_kernel<<<dim3(NTOK/4), dim3(256), 0, stream>>>(x, top_e, top_w, tok_rank, padoff,
                                                        slot_tok, slot_w, Xg);
  moe_g256b<D_MODEL, EXP_D>
      <<<dim3((EXP_D/256)*MAXT256), dim3(512), 131072, stream>>>(
      Xg, Wb, b1, Hb, tileE, meta);
  if (!fusedcvt){
    cvt_kernel<<<dim3(2048), dim3(256), 0, stream>>>(W2, Wb);
  }
  moe_gemm3<EXP_D, D_MODEL, MAXT128H>
      <<<dim3((D_MODEL/256)*MAXT128H), dim3(512), 147456, stream>>>(
      Hb, fusedcvt ? W2b : Wb, b2, out, tileE, meta, slot_w, slot_tok);
}

// Round 15
// 513.515 us; speedup vs baseline: 1.3371x; 1.3371x over previous
//
#include <hip/hip_runtime.h>
#include <stdint.h>

#define D_MODEL 1024
#define EXP_D   4096
#define NE      8
#define NTOK    8192
#define BMT     128
#define MAX_TILES 136
#define MAXT256 72
#define MAXT128H 144

typedef __attribute__((ext_vector_type(8))) short short8;
typedef __attribute__((ext_vector_type(4))) float f32x4;
typedef __attribute__((ext_vector_type(4))) unsigned short us4;

// ---- workspace layout (bytes) ----
#define WS_CURSORS   32         // int[8]
#define WS_PADOFF    64         // int[16]
#define WS_META      128        // int[32], meta[0]=nt (256-tiles), meta[1]=2*nt
#define WS_TILE_E    256        // int[960]
#define WS_PP        4096       // float[2048*8]
#define WS_TOP_E     69632      // int[16384]
#define WS_TOP_W     135168     // float[16384]
#define WS_TOK_RANK  200704     // int[16384]
#define WS_SLOT_W    270336     // float[18432]
#define WS_TOK_SLOT  344064     // int[16384]
#define WS_XG        409600     // bf16 18432 x 1024 (Yb aliases this) -> ends 38,158,336
#define WS_HB        38158336   // bf16 18432 x 4096 -> ends 189,153,280
#define WS_WB        189153280  // bf16 [8][4096][1024] -> ends 256,262,144
#define WS_WB2       256262144  // bf16 [8][1024][4096] (only if ws >= REQ_BIG2)
#define REQ_BIG2     323371008ull

__device__ __forceinline__ unsigned short f2bf(float f){
  __bf16 h = (__bf16)f;
  return __builtin_bit_cast(unsigned short, h);
}
__device__ __forceinline__ float bf2f(unsigned short u){
  unsigned int v = ((unsigned int)u) << 16;
  return __builtin_bit_cast(float, v);
}
__device__ __forceinline__ void gl_lds16(const void* g, void* l){
  __builtin_amdgcn_global_load_lds((const __attribute__((address_space(1))) unsigned int*)g,
                                   (__attribute__((address_space(3))) unsigned int*)l,
                                   16, 0, 0);
}

template<int N> __device__ __forceinline__ void vmw(){
  if constexpr (N==0)      asm volatile("s_waitcnt vmcnt(0)" ::: "memory");
  else if constexpr (N==2) asm volatile("s_waitcnt vmcnt(2)" ::: "memory");
  else if constexpr (N==4) asm volatile("s_waitcnt vmcnt(4)" ::: "memory");
  else if constexpr (N==6) asm volatile("s_waitcnt vmcnt(6)" ::: "memory");
}

// ---------------- router (blocks 0..2047, NO atomics) + weight cvt (blocks >=2048) ----------------
__global__ __launch_bounds__(256) void router_cvt_kernel(
    const float* __restrict__ x, const float* __restrict__ Wr,
    const float* __restrict__ br,
    int* __restrict__ top_e, float* __restrict__ top_w,
    float* __restrict__ pp,
    const float* __restrict__ W1, unsigned short* __restrict__ Wb,
    const float* __restrict__ W2, unsigned short* __restrict__ W2b,
    int cvt_total4)
{
  const int tid = threadIdx.x;
  if ((int)blockIdx.x >= NTOK/4){
    const int n4 = NE*EXP_D*D_MODEL/4;
    const int stride = ((int)gridDim.x - NTOK/4)*256;
    for (int i = ((int)blockIdx.x - NTOK/4)*256 + tid; i < cvt_total4; i += stride){
      if (i < n4){
        const float4 v = *(const float4*)&W1[(size_t)i*4];
        us4 o; o[0]=f2bf(v.x); o[1]=f2bf(v.y); o[2]=f2bf(v.z); o[3]=f2bf(v.w);
        *(us4*)&Wb[(size_t)i*4] = o;
      } else {
        const int j = i - n4;
        const float4 v = *(const float4*)&W2[(size_t)j*4];
        us4 o; o[0]=f2bf(v.x); o[1]=f2bf(v.y); o[2]=f2bf(v.z); o[3]=f2bf(v.w);
        *(us4*)&W2b[(size_t)j*4] = o;
      }
    }
    return;
  }
  __shared__ float WrS[NE*D_MODEL];
  __shared__ float wprob[4][NE];
#pragma unroll
  for (int i=0;i<8;++i){
    int j = (tid + i*256)*4;
    *(float4*)&WrS[j] = *(const float4*)&Wr[j];
  }
  __syncthreads();
  const int w = tid>>6, lane = tid&63;
  const int t = blockIdx.x*4 + w;
  const float* xt = x + (size_t)t*D_MODEL;
  float accv[8] = {0,0,0,0,0,0,0,0};
#pragma unroll
  for (int i=0;i<4;++i){
    const int k = i*256 + lane*4;
    const float4 xv = *(const float4*)&xt[k];
#pragma unroll
    for (int e=0;e<8;++e){
      const float4 wv = *(const float4*)&WrS[e*D_MODEL + k];
      accv[e] += xv.x*wv.x + xv.y*wv.y + xv.z*wv.z + xv.w*wv.w;
    }
  }
#pragma unroll
  for (int m=32;m>0;m>>=1){
#pragma unroll
    for (int e=0;e<8;++e) accv[e] += __shfl_xor(accv[e], m, 64);
  }
  if (lane==0){
    float lg[8];
#pragma unroll
    for (int e=0;e<8;++e) lg[e] = accv[e] + br[e];
    float mx = lg[0];
#pragma unroll
    for (int e=1;e<8;++e) mx = fmaxf(mx, lg[e]);
    float p[8]; float s=0.f;
#pragma unroll
    for (int e=0;e<8;++e){ p[e] = __expf(lg[e]-mx); s += p[e]; }
    const float inv = 1.f/s;
#pragma unroll
    for (int e=0;e<8;++e){ p[e] *= inv; wprob[w][e] = p[e]; }
    int i1=0; float p1v=p[0];
#pragma unroll
    for (int e=1;e<8;++e) if (p[e] > p1v){ p1v=p[e]; i1=e; }
    int i2=-1; float p2v=-1.f;
#pragma unroll
    for (int e=0;e<8;++e) if (e!=i1 && p[e] > p2v){ p2v=p[e]; i2=e; }
    const float rn = 1.f/(p1v+p2v);
    top_e[2*t]   = i1; top_w[2*t]   = p1v*rn;
    top_e[2*t+1] = i2; top_w[2*t+1] = p2v*rn;
  }
  __syncthreads();
  if (tid<8){
    pp[blockIdx.x*8+tid] = wprob[0][tid]+wprob[1][tid]+wprob[2][tid]+wprob[3][tid];
  }
}

// ---------------- standalone cvt (fallback, W2) ----------------
__global__ __launch_bounds__(256) void cvt_kernel(const float* __restrict__ W,
                                                  unsigned short* __restrict__ Wb){
  const int n4 = NE*EXP_D*D_MODEL/4;
  for (int i = blockIdx.x*256 + threadIdx.x; i < n4; i += gridDim.x*256){
    const float4 v = *(const float4*)&W[(size_t)i*4];
    us4 o; o[0]=f2bf(v.x); o[1]=f2bf(v.y); o[2]=f2bf(v.z); o[3]=f2bf(v.w);
    *(us4*)&Wb[(size_t)i*4] = o;
  }
}

// ---------------- scatter: LDS-aggregated counting + expert-local ranks ----------------
__global__ __launch_bounds__(1024) void scatter_kernel(
    const int* __restrict__ top_e,
    int* __restrict__ cursors, int* __restrict__ tok_rank)
{
  __shared__ int cnt[NE];
  __shared__ int base[NE];
  const int tid = threadIdx.x;
  if (tid < NE) cnt[tid] = 0;
  __syncthreads();
  const int t = blockIdx.x*1024 + tid;
  const int e0 = top_e[2*t], e1 = top_e[2*t+1];
  const int p0 = atomicAdd(&cnt[e0], 1);
  const int p1 = atomicAdd(&cnt[e1], 1);
  __syncthreads();
  if (tid < NE) base[tid] = atomicAdd(&cursors[tid], cnt[tid]);
  __syncthreads();
  tok_rank[2*t]   = base[e0] + p0;
  tok_rank[2*t+1] = base[e1] + p1;
}

// ---------------- prefix (AFTER scatter): tile table (256-pad) + aux ----------------
__global__ __launch_bounds__(256) void prefix_kernel(int* __restrict__ wsI,
                                                     const float* __restrict__ pp,
                                                     float* __restrict__ aux_out){
  const int tid = threadIdx.x;
  int* counts = wsI + 8;
  int* padoff = wsI + 16;
  int* meta   = wsI + 32;
  int* tileE  = wsI + 64;
  __shared__ int tileCum[9];
  __shared__ float dev2[8];
  if (tid==0){
    int nt = 0;
    tileCum[0] = 0;
    for (int e=0;e<NE;++e){
      padoff[e] = nt << 8;
      nt += (counts[e] + 255) >> 8;
      tileCum[e+1] = nt;
    }
    meta[0] = nt;
    meta[1] = 2*nt;
  }
  __syncthreads();
  const int nt = tileCum[8];
  for (int i=tid; i<nt; i+=256){
    int e = 0;
    while (tileCum[e+1] <= i) ++e;
    tileE[i] = e;
  }
  const int ex = tid>>5, j = tid&31;
  float s = 0.f;
  for (int b=j; b<NTOK/4; b+=32) s += pp[b*8+ex];
#pragma unroll
  for (int m=16;m>0;m>>=1) s += __shfl_xor(s, m, 64);
  if (j==0){ float d = s*(1.f/(float)NTOK) - 0.125f; dev2[ex] = d*d; }
  __syncthreads();
  if (tid==0){
    float a=0.f;
#pragma unroll
    for (int e=0;e<8;++e) a += dev2[e];
    aux_out[0] = a;
  }
}

// ---------------- gather: slot = padoff[e] + rank; write tok_slot/slot_w/Xg rows ----------------
__global__ __launch_bounds__(256) void gather_kernel(
    const float* __restrict__ x, const int* __restrict__ top_e,
    const float* __restrict__ top_w, const int* __restrict__ tok_rank,
    const int* __restrict__ padoff,
    int* __restrict__ tok_slot, float* __restrict__ slot_w,
    unsigned short* __restrict__ Xg)
{
  const int w = threadIdx.x>>6, lane = threadIdx.x&63;
  const int t = blockIdx.x*4 + w;
  const int s0 = padoff[top_e[2*t]]   + tok_rank[2*t];
  const int s1 = padoff[top_e[2*t+1]] + tok_rank[2*t+1];
  if (lane==0){
    tok_slot[2*t] = s0; tok_slot[2*t+1] = s1;
    slot_w[s0] = top_w[2*t]; slot_w[s1] = top_w[2*t+1];
  }
  us4 o[4];
#pragma unroll
  for (int i=0;i<4;++i){
    const float4 v = *(const float4*)&x[(size_t)t*D_MODEL + i*256 + lane*4];
    o[i][0]=f2bf(v.x); o[i][1]=f2bf(v.y); o[i][2]=f2bf(v.z); o[i][3]=f2bf(v.w);
  }
#pragma unroll
  for (int i=0;i<4;++i) *(us4*)&Xg[(size_t)s0*D_MODEL + i*256 + lane*4] = o[i];
#pragma unroll
  for (int i=0;i<4;++i) *(us4*)&Xg[(size_t)s1*D_MODEL + i*256 + lane*4] = o[i];
}

// ============ GEMM1: 256x256 tile, BK=64, 8 waves (128x64/wave), 2-buf, 4 fine phases ============
template<int KT, int NT>
__global__ __launch_bounds__(512,1) void moe_g256(
    const unsigned short* __restrict__ A,
    const unsigned short* __restrict__ Wb,
    const float* __restrict__ bias,
    unsigned short* __restrict__ Cout,
    const int* __restrict__ tileE,
    const int* __restrict__ meta)
{
  constexpr int NX = NT/256;
  constexpr int TOTAL = NX*MAXT256;
  constexpr int Q = TOTAL/8, R = TOTAL%8;
  constexpr int NTILES = KT/64;
  static_assert(NTILES%2==0 && NTILES>=4, "even K-tiles");

  const int lid = blockIdx.x;
  const int xcc = lid & 7, jj = lid >> 3;
  const int tsw = xcc*Q + (xcc < R ? xcc : R) + jj;
  const int mtile = tsw / NX, ntile = tsw - mtile*NX;
  if (mtile >= meta[0]) return;

  extern __shared__ char smem[];
  char* const BUF0 = smem;
  char* const BUF1 = smem + 65536;

  const int tid = threadIdx.x;
  const int w = tid>>6, lane = tid&63;
  const int wr = w>>2, wn = w&3;
  const int r15 = lane&15, kg = lane>>4;
  const int e  = tileE[mtile];
  const int m0 = mtile*256;
  const int n0 = ntile*256;

  const int trow = tid>>3;
  const int tch  = ((tid&7) ^ (trow&7))*8;
  const unsigned short* sA = A  + (size_t)(m0 + trow)*KT + tch;
  const unsigned short* sB = Wb + (size_t)e*NT*KT + (size_t)(n0 + trow)*KT + tch;

#define SG_B01(BS,KTT) do{ \
  gl_lds16(sB + (size_t)(KTT)*64,                  (BS)+32768+tid*16); \
  gl_lds16(sB + (size_t)(KTT)*64 + (size_t)64*KT,  (BS)+40960+tid*16); }while(0)
#define SG_B23(BS,KTT) do{ \
  gl_lds16(sB + (size_t)(KTT)*64 + (size_t)128*KT, (BS)+49152+tid*16); \
  gl_lds16(sB + (size_t)(KTT)*64 + (size_t)192*KT, (BS)+57344+tid*16); }while(0)
#define SG_A02(BS,KTT) do{ \
  gl_lds16(sA + (size_t)(KTT)*64,                  (BS)+tid*16); \
  gl_lds16(sA + (size_t)(KTT)*64 + (size_t)128*KT, (BS)+16384+tid*16); }while(0)
#define SG_A13(BS,KTT) do{ \
  gl_lds16(sA + (size_t)(KTT)*64 + (size_t)64*KT,  (BS)+8192+tid*16); \
  gl_lds16(sA + (size_t)(KTT)*64 + (size_t)192*KT, (BS)+24576+tid*16); }while(0)

  const int key4 = (kg ^ (r15&7))<<4;
  const int aw = (wr*128 + r15)*128 + key4;          // + qb*128 + mi*2048
  const int bw = 32768 + (wn*64 + r15)*128 + key4;   // + nf*2048

  f32x4 acc[8][4];
#pragma unroll
  for (int i=0;i<8;++i)
#pragma unroll
    for (int j=0;j<4;++j) acc[i][j] = (f32x4){0.f,0.f,0.f,0.f};

  short8 Aq[8], Bq[4];

#define RD_A(BC, QB) do{ _Pragma("unroll") for(int mi=0;mi<4;++mi){ \
    const int off_ = aw + (QB)*128 + mi*2048; \
    Aq[mi*2]   = *(const short8*)((BC)+off_); \
    Aq[mi*2+1] = *(const short8*)((BC)+(off_^64)); }}while(0)
#define RD_B(BC, NF0) do{ _Pragma("unroll") for(int nf=0;nf<2;++nf){ \
    const int off_ = bw + ((NF0)+nf)*2048; \
    Bq[nf*2]   = *(const short8*)((BC)+off_); \
    Bq[nf*2+1] = *(const short8*)((BC)+(off_^64)); }}while(0)

#define MFQ(MB, NF0) \
  _Pragma("unroll") for(int mi=0;mi<4;++mi) \
  _Pragma("unroll") for(int nf=0;nf<2;++nf){ \
    acc[(MB)+mi][(NF0)+nf]=__builtin_amdgcn_mfma_f32_16x16x32_bf16(Bq[nf*2],Aq[mi*2],acc[(MB)+mi][(NF0)+nf],0,0,0); \
    acc[(MB)+mi][(NF0)+nf]=__builtin_amdgcn_mfma_f32_16x16x32_bf16(Bq[nf*2+1],Aq[mi*2+1],acc[(MB)+mi][(NF0)+nf],0,0,0); }

#define PH_TAIL(MFS) \
    __builtin_amdgcn_sched_barrier(0); \
    __builtin_amdgcn_s_barrier(); \
    asm volatile("s_waitcnt lgkmcnt(0)" ::: "memory"); \
    __builtin_amdgcn_sched_barrier(0); \
    __builtin_amdgcn_s_setprio(1); \
    MFS \
    __builtin_amdgcn_s_setprio(0); \
    __builtin_amdgcn_sched_barrier(0); \
    __builtin_amdgcn_s_barrier();

#define T256(BC,BS,KTN,DOSTG,VM1,VM3) do{ \
    RD_A(BC,0); RD_B(BC,0); if(DOSTG){ SG_B01(BS,KTN); } \
    PH_TAIL(MFQ(0,0)) \
    RD_B(BC,2); if(DOSTG){ SG_B23(BS,KTN); } \
    VM1; \
    PH_TAIL(MFQ(0,2)) \
    RD_A(BC,64); RD_B(BC,0); if(DOSTG){ SG_A02(BS,KTN); } \
    PH_TAIL(MFQ(4,0)) \
    RD_B(BC,2); if(DOSTG){ SG_A13(BS,KTN); } \
    VM3; \
    PH_TAIL(MFQ(4,2)) \
  }while(0)

  SG_B01(BUF0,0); SG_B23(BUF0,0); SG_A02(BUF0,0); SG_A13(BUF0,0);
  vmw<2>();
  __builtin_amdgcn_s_barrier();

#pragma unroll 1
  for (int i = 0; i < (NTILES-2)/2; ++i){
    T256(BUF0, BUF1, 2*i+1, true, vmw<4>(), vmw<2>());
    T256(BUF1, BUF0, 2*i+2, true, vmw<4>(), vmw<2>());
  }
  T256(BUF0, BUF1, NTILES-1, true, vmw<4>(), vmw<2>());  // tile NTILES-2
  T256(BUF1, BUF0, 0, false, vmw<0>(), (void)0);         // tile NTILES-1
#undef T256
#undef PH_TAIL
#undef MFQ
#undef RD_A
#undef RD_B
#undef SG_B01
#undef SG_B23
#undef SG_A02
#undef SG_A13

  const int ng4 = kg*4;
#pragma unroll
  for (int mi=0; mi<8; ++mi){
    const int m = m0 + wr*128 + mi*16 + r15;
#pragma unroll
    for (int nf=0; nf<4; ++nf){
      const int nb = n0 + wn*64 + nf*16 + ng4;
      const float4 bv = *(const float4*)&bias[(size_t)e*NT + nb];
      float q0 = fmaxf(acc[mi][nf][0] + bv.x, 0.f);
      float q1 = fmaxf(acc[mi][nf][1] + bv.y, 0.f);
      float q2 = fmaxf(acc[mi][nf][2] + bv.z, 0.f);
      float q3 = fmaxf(acc[mi][nf][3] + bv.w, 0.f);
      us4 o; o[0]=f2bf(q0); o[1]=f2bf(q1); o[2]=f2bf(q2); o[3]=f2bf(q3);
      *(us4*)&Cout[(size_t)m*NT + nb] = o;
    }
  }
}

// ============ GEMM2: 128x256, BK=64, 8 waves, 3-buf pipeline (proven) ============
template<int KT, int NT, int MAXT>
__global__ __launch_bounds__(512,1) void moe_gemm3(
    const unsigned short* __restrict__ A,
    const unsigned short* __restrict__ Wb,
    const float* __restrict__ bias,
    unsigned short* __restrict__ Cout,
    const int* __restrict__ tileE,
    const int* __restrict__ meta,
    const float* __restrict__ slotw)
{
  constexpr int NX = NT/256;
  constexpr int TOTAL = NX*MAXT;
  constexpr int Q = TOTAL/8, R = TOTAL%8;
  constexpr int NTILES = KT/64;
  constexpr int K3 = (NTILES-4)/3;
  static_assert((NTILES-4)%3 == 0, "tail peel needs (NTILES-4)%3==0");

  const int lid = blockIdx.x;
  const int xcc = lid & 7, jj = lid >> 3;
  const int tsw = xcc*Q + (xcc < R ? xcc : R) + jj;
  const int mtile = tsw / NX, ntile = tsw - mtile*NX;
  if (mtile >= meta[1]) return;

  extern __shared__ char smem[];
  char* const BUF0 = smem;
  char* const BUF1 = smem + 49152;
  char* const BUF2 = smem + 98304;

  const int tid = threadIdx.x;
  const int w = tid>>6, lane = tid&63;
  const int wr = w>>2, wn = w&3;
  const int r15 = lane&15, kg = lane>>4;
  const int e  = tileE[mtile>>1];
  const int m0 = mtile*BMT;
  const int n0 = ntile*256;

  const int trow = tid>>3;
  const int tch  = ((tid&7) ^ (trow&7))*8;
  const unsigned short* sA = A  + (size_t)(m0 + trow)*KT + tch;
  const unsigned short* sB = Wb + (size_t)e*NT*KT + (size_t)(n0 + trow)*KT + tch;

#define STG_ALL(BS, KTT) do{ \
    gl_lds16(sA + (size_t)(KTT)*64,                  (BS) + tid*16); \
    gl_lds16(sA + (size_t)(KTT)*64 + (size_t)64*KT,  (BS) + 8192  + tid*16); \
    gl_lds16(sB + (size_t)(KTT)*64,                  (BS) + 16384 + tid*16); \
    gl_lds16(sB + (size_t)(KTT)*64 + (size_t)64*KT,  (BS) + 24576 + tid*16); \
    gl_lds16(sB + (size_t)(KTT)*64 + (size_t)128*KT, (BS) + 32768 + tid*16); \
    gl_lds16(sB + (size_t)(KTT)*64 + (size_t)192*KT, (BS) + 40960 + tid*16); \
  }while(0)

  const int key4 = (kg ^ (r15&7))<<4;
  const int a0 = (wr*64 + 0*16 + r15)*128 + key4;
  const int a1 = (wr*64 + 1*16 + r15)*128 + key4;
  const int a2 = (wr*64 + 2*16 + r15)*128 + key4;
  const int a3 = (wr*64 + 3*16 + r15)*128 + key4;
  const int b0 = 16384 + (wn*64 + 0*16 + r15)*128 + key4;
  const int b1 = 16384 + (wn*64 + 1*16 + r15)*128 + key4;
  const int b2 = 16384 + (wn*64 + 2*16 + r15)*128 + key4;
  const int b3 = 16384 + (wn*64 + 3*16 + r15)*128 + key4;

  f32x4 acc[4][4];
#pragma unroll
  for (int i=0;i<4;++i)
#pragma unroll
    for (int j=0;j<4;++j) acc[i][j] = (f32x4){0.f,0.f,0.f,0.f};

  short8 A0[4], B0[4], A1[4], B1[4];

#define MFMA16(AX, BX) \
    acc[0][0]=__builtin_amdgcn_mfma_f32_16x16x32_bf16(BX[0],AX[0],acc[0][0],0,0,0); \
    acc[0][1]=__builtin_amdgcn_mfma_f32_16x16x32_bf16(BX[1],AX[0],acc[0][1],0,0,0); \
    acc[0][2]=__builtin_amdgcn_mfma_f32_16x16x32_bf16(BX[2],AX[0],acc[0][2],0,0,0); \
    acc[0][3]=__builtin_amdgcn_mfma_f32_16x16x32_bf16(BX[3],AX[0],acc[0][3],0,0,0); \
    acc[1][0]=__builtin_amdgcn_mfma_f32_16x16x32_bf16(BX[0],AX[1],acc[1][0],0,0,0); \
    acc[1][1]=__builtin_amdgcn_mfma_f32_16x16x32_bf16(BX[1],AX[1],acc[1][1],0,0,0); \
    acc[1][2]=__builtin_amdgcn_mfma_f32_16x16x32_bf16(BX[2],AX[1],acc[1][2],0,0,0); \
    acc[1][3]=__builtin_amdgcn_mfma_f32_16x16x32_bf16(BX[3],AX[1],acc[1][3],0,0,0); \
    acc[2][0]=__builtin_amdgcn_mfma_f32_16x16x32_bf16(BX[0],AX[2],acc[2][0],0,0,0); \
    acc[2][1]=__builtin_amdgcn_mfma_f32_16x16x32_bf16(BX[1],AX[2],acc[2][1],0,0,0); \
    acc[2][2]=__builtin_amdgcn_mfma_f32_16x16x32_bf16(BX[2],AX[2],acc[2][2],0,0,0); \
    acc[2][3]=__builtin_amdgcn_mfma_f32_16x16x32_bf16(BX[3],AX[2],acc[2][3],0,0,0); \
    acc[3][0]=__builtin_amdgcn_mfma_f32_16x16x32_bf16(BX[0],AX[3],acc[3][0],0,0,0); \
    acc[3][1]=__builtin_amdgcn_mfma_f32_16x16x32_bf16(BX[1],AX[3],acc[3][1],0,0,0); \
    acc[3][2]=__builtin_amdgcn_mfma_f32_16x16x32_bf16(BX[2],AX[3],acc[3][2],0,0,0); \
    acc[3][3]=__builtin_amdgcn_mfma_f32_16x16x32_bf16(BX[3],AX[3],acc[3][3],0,0,0);

#define RD_KS1(BC) do{ \
    A1[0] = *(const short8*)((BC) + (a0 ^ 64)); \
    A1[1] = *(const short8*)((BC) + (a1 ^ 64)); \
    A1[2] = *(const short8*)((BC) + (a2 ^ 64)); \
    A1[3] = *(const short8*)((BC) + (a3 ^ 64)); \
    B1[0] = *(const short8*)((BC) + (b0 ^ 64)); \
    B1[1] = *(const short8*)((BC) + (b1 ^ 64)); \
    B1[2] = *(const short8*)((BC) + (b2 ^ 64)); \
    B1[3] = *(const short8*)((BC) + (b3 ^ 64)); \
  }while(0)
#define RD_KS0(BN1) do{ \
    A0[0] = *(const short8*)((BN1) + a0); \
    A0[1] = *(const short8*)((BN1) + a1); \
    A0[2] = *(const short8*)((BN1) + a2); \
    A0[3] = *(const short8*)((BN1) + a3); \
    B0[0] = *(const short8*)((BN1) + b0); \
    B0[1] = *(const short8*)((BN1) + b1); \
    B0[2] = *(const short8*)((BN1) + b2); \
    B0[3] = *(const short8*)((BN1) + b3); \
  }while(0)

#define TILE(BC, BN1, STG_STMT, VM_STMT) do{ \
    RD_KS1(BC); \
    STG_STMT; \
    __builtin_amdgcn_sched_barrier(0); \
    __builtin_amdgcn_s_setprio(1); \
    MFMA16(A0, B0) \
    __builtin_amdgcn_s_setprio(0); \
    __builtin_amdgcn_sched_barrier(0); \
    VM_STMT; \
    asm volatile("s_waitcnt lgkmcnt(0)" ::: "memory"); \
    __builtin_amdgcn_sched_barrier(0); \
    __builtin_amdgcn_s_barrier(); \
    RD_KS0(BN1); \
    __builtin_amdgcn_sched_barrier(0); \
    __builtin_amdgcn_s_setprio(1); \
    MFMA16(A1, B1) \
    __builtin_amdgcn_s_setprio(0); \
    __builtin_amdgcn_sched_barrier(0); \
  }while(0)

  STG_ALL(BUF0, 0);
  STG_ALL(BUF1, 1);
  vmw<6>();
  __builtin_amdgcn_s_barrier();
  RD_KS0(BUF0);

#pragma unroll 1
  for (int i = 0; i < K3; ++i){
    const int kt = i*3;
    TILE(BUF0, BUF1, STG_ALL(BUF2, kt+2), vmw<6>());
    TILE(BUF1, BUF2, STG_ALL(BUF0, kt+3), vmw<6>());
    TILE(BUF2, BUF0, STG_ALL(BUF1, kt+4), vmw<6>());
  }
  TILE(BUF0, BUF1, STG_ALL(BUF2, NTILES-2), vmw<6>());
  TILE(BUF1, BUF2, STG_ALL(BUF0, NTILES-1), vmw<6>());
  TILE(BUF2, BUF0, (void)0, vmw<0>());
  {
    RD_KS1(BUF0);
    __builtin_amdgcn_sched_barrier(0);
    __builtin_amdgcn_s_setprio(1);
    MFMA16(A0, B0)
    __builtin_amdgcn_s_setprio(0);
    __builtin_amdgcn_sched_barrier(0);
    __builtin_amdgcn_s_setprio(1);
    MFMA16(A1, B1)
    __builtin_amdgcn_s_setprio(0);
  }
#undef TILE
#undef RD_KS0
#undef RD_KS1
#undef MFMA16
#undef STG_ALL

  const int ng4 = kg*4;
#pragma unroll
  for (int mf=0; mf<4; ++mf){
    const int m = m0 + wr*64 + mf*16 + r15;
    const float wg = slotw[m];
#pragma unroll
    for (int nf=0; nf<4; ++nf){
      const int nb = n0 + wn*64 + nf*16 + ng4;
      const float4 bv = *(const float4*)&bias[(size_t)e*NT + nb];
      float q0 = (acc[mf][nf][0] + bv.x)*wg;
      float q1 = (acc[mf][nf][1] + bv.y)*wg;
      float q2 = (acc[mf][nf][2] + bv.z)*wg;
      float q3 = (acc[mf][nf][3] + bv.w)*wg;
      us4 o; o[0]=f2bf(q0); o[1]=f2bf(q1); o[2]=f2bf(q2); o[3]=f2bf(q3);
      *(us4*)&Cout[(size_t)m*NT + nb] = o;
    }
  }
}

// ---------------- combine: out[t] = Y[slot0] + Y[slot1] ----------------
__global__ __launch_bounds__(256) void combine_kernel(
    const unsigned short* __restrict__ Yb, const int* __restrict__ tok_slot,
    float* __restrict__ out)
{
  const int t = blockIdx.x;
  const int tid = threadIdx.x;
  const int s0 = tok_slot[2*t], s1 = tok_slot[2*t+1];
  const us4 a = *(const us4*)&Yb[(size_t)s0*D_MODEL + tid*4];
  const us4 b = *(const us4*)&Yb[(size_t)s1*D_MODEL + tid*4];
  float4 o;
  o.x = bf2f(a[0]) + bf2f(b[0]);
  o.y = bf2f(a[1]) + bf2f(b[1]);
  o.z = bf2f(a[2]) + bf2f(b[2]);
  o.w = bf2f(a[3]) + bf2f(b[3]);
  *(float4*)&out[(size_t)t*D_MODEL + tid*4] = o;
}

extern "C" void kernel_launch(void* const* d_in, const int* in_sizes, int n_in,
                              void* d_out, int out_size, void* d_ws, size_t ws_size,
                              hipStream_t stream)
{
  const float* x  = (const float*)d_in[0];
  const float* Wr = (const float*)d_in[1];
  const float* br = (const float*)d_in[2];
  const float* W1 = (const float*)d_in[3];
  const float* b1 = (const float*)d_in[4];
  const float* W2 = (const float*)d_in[5];
  const float* b2 = (const float*)d_in[6];
  float* out = (float*)d_out;
  char* ws = (char*)d_ws;

  const bool fusedcvt = ws_size >= REQ_BIG2;

  int*   cursors = (int*)(ws + WS_CURSORS);
  int*   padoff  = (int*)(ws + WS_PADOFF);
  int*   meta    = (int*)(ws + WS_META);
  int*   tileE   = (int*)(ws + WS_TILE_E);
  float* pp      = (float*)(ws + WS_PP);
  int*   top_e   = (int*)(ws + WS_TOP_E);
  float* top_w   = (float*)(ws + WS_TOP_W);
  int*   tok_rank= (int*)(ws + WS_TOK_RANK);
  float* slot_w  = (float*)(ws + WS_SLOT_W);
  int*   tok_slot= (int*)(ws + WS_TOK_SLOT);
  unsigned short* Xg  = (unsigned short*)(ws + WS_XG);
  unsigned short* Hb  = (unsigned short*)(ws + WS_HB);
  unsigned short* Wb  = (unsigned short*)(ws + WS_WB);
  unsigned short* W2b = (unsigned short*)(ws + WS_WB2);
  unsigned short* Yb  = Xg;   // Xg dead after GEMM1

  hipFuncSetAttribute((const void*)moe_g256<D_MODEL, EXP_D>,
                      hipFuncAttributeMaxDynamicSharedMemorySize, 131072);
  hipFuncSetAttribute((const void*)moe_gemm3<EXP_D, D_MODEL, MAXT128H>,
                      hipFuncAttributeMaxDynamicSharedMemorySize, 147456);

  const int n4 = NE*EXP_D*D_MODEL/4;
  hipMemsetAsync(ws, 0, 128, stream);   // cursors zero
  if (fusedcvt){
    router_cvt_kernel<<<dim3(NTOK/4 + 4096), dim3(256), 0, stream>>>(
        x, Wr, br, top_e, top_w, pp, W1, Wb, W2, W2b, 2*n4);
  } else {
    router_cvt_kernel<<<dim3(NTOK/4 + 2048), dim3(256), 0, stream>>>(
        x, Wr, br, top_e, top_w, pp, W1, Wb, W2, Wb, n4);
  }
  scatter_kernel<<<dim3(NTOK/1024), dim3(1024), 0, stream>>>(top_e, cursors, tok_rank);
  prefix_kernel<<<dim3(1), dim3(256), 0, stream>>>((int*)ws, pp, out + (size_t)NTOK*D_MODEL);
  gather_kernel<<<dim3(NTOK/4), dim3(256), 0, stream>>>(x, top_e, top_w, tok_rank, padoff,
                                                        tok_slot, slot_w, Xg);
  moe_g256<D_MODEL, EXP_D>
      <<<dim3((EXP_D/256)*MAXT256), dim3(512), 131072, stream>>>(
      Xg, Wb, b1, Hb, tileE, meta);
  if (!fusedcvt){
    cvt_kernel<<<dim3(2048), dim3(256), 0, stream>>>(W2, Wb);
  }
  moe_gemm3<EXP_D, D_MODEL, MAXT128H>
      <<<dim3((D_MODEL/256)*MAXT128H), dim3(512), 147456, stream>>>(
      Hb, fusedcvt ? W2b : Wb, b2, Yb, tileE, meta, slot_w);
  combine_kernel<<<dim3(NTOK), dim3(256), 0, stream>>>(Yb, tok_slot, out);
}